// Round 3
// baseline (94.388 us; speedup 1.0000x reference)
//
#include <hip/hip_runtime.h>

// f = -grad_p sum(mlp(p)); mlp: 2->8 relu ->4 relu ->2 (no bias on last).
// Force is PIECEWISE CONSTANT in p (depends only on the 12 ReLU sign bits).
// The harness's np reference runs in fp32 (numpy keeps input dtype; matmul ->
// OpenBLAS sgemm). To match every mask bit we replicate sgemm's arithmetic
// bit-exactly: k-ascending FMA accumulation starting at 0, bias added as a
// SEPARATE fp32 add (separate numpy op). The post-mask gradient combination is
// piecewise-constant -> any fp32 order is fine vs the 2% threshold.
//
// Layouts (row-major, per JAX): W1 [8,2], b1 [8], W2 [4,8], b2 [4], W3 [2,4]
// out: [N,2] float32.

__global__ __launch_bounds__(256) void toy_force_kernel(
    const float4* __restrict__ pos4,
    const float*  __restrict__ W1,
    const float*  __restrict__ b1,
    const float*  __restrict__ W2,
    const float*  __restrict__ b2,
    const float*  __restrict__ W3,
    float4* __restrict__ out4,
    int n4)
{
    // Uniform weight loads -> scalar loads, L1-resident.
    float w1x[8], w1y[8], bb1[8];
    float w2[4][8], bb2[4], g2base[4];
#pragma unroll
    for (int k = 0; k < 8; ++k) {
        w1x[k] = W1[2 * k];
        w1y[k] = W1[2 * k + 1];
        bb1[k] = b1[k];
    }
#pragma unroll
    for (int j = 0; j < 4; ++j) {
#pragma unroll
        for (int k = 0; k < 8; ++k) w2[j][k] = W2[8 * j + k];
        bb2[j]    = b2[j];
        g2base[j] = W3[j] + W3[4 + j];   // ones @ W3 (dE/dh2 before relu mask)
    }

    int i = blockIdx.x * blockDim.x + threadIdx.x;
    if (i >= n4) return;

    float4 p = pos4[i];
    float o[4];

#pragma unroll
    for (int t = 0; t < 2; ++t) {
        float px = t ? p.z : p.x;
        float py = t ? p.w : p.y;

        // --- layer 1, numpy/sgemm bit-exact ---
        // sgemm K=2: acc = fma(p1, w1, fma(p0, w0, 0)) = fma(p1, w1, RN(p0*w0));
        // bias is a separate numpy add.
        float z1[8], a1[8];
#pragma unroll
        for (int k = 0; k < 8; ++k) {
            float dot = fmaf(py, w1y[k], px * w1x[k]);
            z1[k] = dot + bb1[k];
            a1[k] = fmaxf(z1[k], 0.0f);
        }

        // --- layer 2, numpy/sgemm bit-exact: k-ascending fma from 0, + bias ---
        float g2[4];
#pragma unroll
        for (int j = 0; j < 4; ++j) {
            float acc = 0.0f;
#pragma unroll
            for (int k = 0; k < 8; ++k) acc = fmaf(a1[k], w2[j][k], acc);
            float z2 = acc + bb2[j];
            g2[j] = (z2 > 0.0f) ? g2base[j] : 0.0f;
        }

        // --- backward (piecewise-constant in weights), any fp32 order ---
        float fx = 0.0f, fy = 0.0f;
#pragma unroll
        for (int k = 0; k < 8; ++k) {
            float g1 = 0.0f;
#pragma unroll
            for (int j = 0; j < 4; ++j) g1 = fmaf(g2[j], w2[j][k], g1);
            g1 = (z1[k] > 0.0f) ? g1 : 0.0f;
            fx = fmaf(g1, w1x[k], fx);
            fy = fmaf(g1, w1y[k], fy);
        }

        o[2 * t]     = -fx;
        o[2 * t + 1] = -fy;
    }

    out4[i] = make_float4(o[0], o[1], o[2], o[3]);
}

extern "C" void kernel_launch(void* const* d_in, const int* in_sizes, int n_in,
                              void* d_out, int out_size, void* d_ws, size_t ws_size,
                              hipStream_t stream) {
    const float* pos = (const float*)d_in[0];
    const float* W1  = (const float*)d_in[1];
    const float* b1  = (const float*)d_in[2];
    const float* W2  = (const float*)d_in[3];
    const float* b2  = (const float*)d_in[4];
    const float* W3  = (const float*)d_in[5];
    float* out = (float*)d_out;

    int n4 = in_sizes[0] / 4;              // 2,097,152 float4 (2 positions each)
    int block = 256;
    int grid = (n4 + block - 1) / block;   // 8192 blocks

    toy_force_kernel<<<grid, block, 0, stream>>>(
        (const float4*)pos, W1, b1, W2, b2, W3, (float4*)out, n4);
}